// Round 1
// baseline (40.250 us; speedup 1.0000x reference)
//
#include <hip/hip_runtime.h>

#define DEV __device__ __forceinline__

DEV float ex2(float x) { return __builtin_amdgcn_exp2f(x); }
DEV float rcp(float x) { return __builtin_amdgcn_rcpf(x); }

// out[b][o] = sum_i ( sum_g basis*w ) + bias[o]
// basis_g = e_g / (sum_g e_g + eps), e_g = exp(-|tanh(x/sc) - grid_g|^3)
// Block: 256 threads = 4 waves; wave -> one (b,o); lanes split I.
__global__ __launch_bounds__(256, 4)
void kan_g8(const float* __restrict__ x, const float* __restrict__ w,
            const float* __restrict__ sc, const float* __restrict__ bias,
            const float* __restrict__ gp, float* __restrict__ out,
            int B, int I, int O)
{
    constexpr float LOG2E      = 1.4426950408889634f;
    constexpr float CBRT_LOG2E = 1.1299472940779f;   // cbrt(log2(e)), verified ^3 == LOG2E
    const int o    = blockIdx.x;
    const int wid  = threadIdx.x >> 6;
    const int lane = threadIdx.x & 63;
    const int b    = blockIdx.y * 4 + wid;
    if (b >= B) return;

    float gs[8];
#pragma unroll
    for (int g = 0; g < 8; ++g) gs[g] = gp[g] * CBRT_LOG2E;

    const int nk = I >> 6;
    float acc = 0.f;
    for (int k = 0; k < nk; ++k) {
        const int i  = (k << 6) + lane;
        const float xv = x[(size_t)b * I + i];
        const float sv = sc[(size_t)o * I + i];
        const float t  = xv * rcp(sv);
        // tanh(t) = sign(t) * (1 - e) / (1 + e), e = exp(-2|t|)
        const float at = fabsf(t);
        const float e  = ex2(-2.f * LOG2E * at);
        const float th = (1.f - e) * rcp(1.f + e);
        const float xn = __builtin_copysignf(th, t);
        const float ts = xn * CBRT_LOG2E;           // pre-scaled so exp(-d^3)=exp2(-(ts-gs)^3)

        const float4* wp = (const float4*)(w + ((size_t)o * I + i) * 8);
        const float4 w0 = wp[0];
        const float4 w1 = wp[1];

        float bb[8];
        float den = 1e-8f;
#pragma unroll
        for (int g = 0; g < 8; ++g) {
            const float d  = fabsf(ts - gs[g]);
            const float d3 = d * d * d;
            bb[g] = ex2(-d3);
            den += bb[g];
        }
        const float num = bb[0]*w0.x + bb[1]*w0.y + bb[2]*w0.z + bb[3]*w0.w
                        + bb[4]*w1.x + bb[5]*w1.y + bb[6]*w1.z + bb[7]*w1.w;
        acc += num * rcp(den);
    }
    // wave64 butterfly reduce
#pragma unroll
    for (int off = 32; off; off >>= 1) acc += __shfl_xor(acc, off, 64);
    if (lane == 0) out[(size_t)b * O + o] = acc + bias[o];
}

// Generic fallback (any G, any I) — correctness safety net only.
__global__ void kan_generic(const float* __restrict__ x, const float* __restrict__ w,
                            const float* __restrict__ sc, const float* __restrict__ bias,
                            const float* __restrict__ gp, float* __restrict__ out,
                            int B, int I, int O, int G)
{
    constexpr float LOG2E = 1.4426950408889634f;
    const int o    = blockIdx.x;
    const int wid  = threadIdx.x >> 6;
    const int lane = threadIdx.x & 63;
    const int b    = blockIdx.y * 4 + wid;
    if (b >= B) return;

    float acc = 0.f;
    for (int i = lane; i < I; i += 64) {
        const float xv = x[(size_t)b * I + i];
        const float sv = sc[(size_t)o * I + i];
        const float t  = xv / sv;
        const float at = fabsf(t);
        const float e  = ex2(-2.f * LOG2E * at);
        const float th = (1.f - e) / (1.f + e);
        const float xn = __builtin_copysignf(th, t);
        float den = 1e-8f, num = 0.f;
        for (int g = 0; g < G; ++g) {
            const float d  = fabsf(xn - gp[g]);
            const float d3 = d * d * d;
            const float bb = ex2(-d3 * LOG2E);
            den += bb;
            num += bb * w[((size_t)o * I + i) * G + g];
        }
        acc += num / den;
    }
#pragma unroll
    for (int off = 32; off; off >>= 1) acc += __shfl_xor(acc, off, 64);
    if (lane == 0) out[(size_t)b * O + o] = acc + bias[o];
}

extern "C" void kernel_launch(void* const* d_in, const int* in_sizes, int n_in,
                              void* d_out, int out_size, void* d_ws, size_t ws_size,
                              hipStream_t stream) {
    const float* x    = (const float*)d_in[0];
    const float* w    = (const float*)d_in[1];
    const float* sc   = (const float*)d_in[2];
    const float* bias = (const float*)d_in[3];
    const float* gp   = (const float*)d_in[4];
    float* out = (float*)d_out;

    const int O = in_sizes[3];
    const int G = in_sizes[4];
    const int I = in_sizes[2] / O;
    const int B = in_sizes[0] / I;

    dim3 grid(O, (B + 3) / 4);
    if (G == 8 && (I & 63) == 0) {
        kan_g8<<<grid, 256, 0, stream>>>(x, w, sc, bias, gp, out, B, I, O);
    } else {
        kan_generic<<<grid, 256, 0, stream>>>(x, w, sc, bias, gp, out, B, I, O, G);
    }
}

// Round 2
// 28.925 us; speedup vs baseline: 1.3916x; 1.3916x over previous
//
#include <hip/hip_runtime.h>
#include <hip/hip_fp16.h>

#define DEV __device__ __forceinline__
DEV float ex2(float x)  { return __builtin_amdgcn_exp2f(x); }
DEV float rcpa(float x) { return __builtin_amdgcn_rcpf(x); }

constexpr int   T_ENT  = 2048;                 // table entries over xn in [-1,1]
constexpr float LOG2E  = 1.4426950408889634f;

// Table-driven KAN: normalized basis nb(xn) in R^8 is a pure function of
// xn = tanh(x/sc); tabulate (fp16, nearest-neighbor) in LDS per block.
// Block = (o, 32 b's): 4 waves x 8 b each; lanes split I.
__global__ __launch_bounds__(256)
void kan_tbl(const float* __restrict__ x, const float* __restrict__ w,
             const float* __restrict__ sc, const float* __restrict__ bias,
             const float* __restrict__ gp, float* __restrict__ out,
             int B, int I, int O)
{
    __shared__ float4 tbl[T_ENT];              // 8 fp16 per entry = 16 B -> 32 KB

    // ---- build normalized-basis table (cheap: 8 entries/thread) ----
    float g8[8];
#pragma unroll
    for (int g = 0; g < 8; ++g) g8[g] = gp[g];
    for (int e = threadIdx.x; e < T_ENT; e += blockDim.x) {
        const float xn = -1.f + 2.f * (float)e / (float)(T_ENT - 1);
        float bb[8]; float den = 1e-8f;
#pragma unroll
        for (int g = 0; g < 8; ++g) {
            const float d = fabsf(xn - g8[g]);
            bb[g] = ex2(-(d * d * d) * LOG2E);   // exp(-d^3)
            den += bb[g];
        }
        const float rd = 1.f / den;
        union { float4 f4; __half2 h2[4]; } u;
#pragma unroll
        for (int j = 0; j < 4; ++j)
            u.h2[j] = __floats2half2_rn(bb[2*j] * rd, bb[2*j+1] * rd);
        tbl[e] = u.f4;
    }
    __syncthreads();

    const int o    = blockIdx.x;
    const int wid  = threadIdx.x >> 6;
    const int lane = threadIdx.x & 63;
    const int b0   = (blockIdx.y * 4 + wid) * 8;   // 8 b's per wave
    if (b0 >= B) return;

    float acc[8] = {0.f,0.f,0.f,0.f,0.f,0.f,0.f,0.f};
    const int nk = I >> 6;
    const float K2 = 2.f * LOG2E;
    for (int k = 0; k < nk; ++k) {
        const int i = (k << 6) + lane;
        const float rs2 = K2 * rcpa(sc[(size_t)o * I + i]);
        const float4* wp = (const float4*)(w + ((size_t)o * I + i) * 8);
        const float4 w0 = wp[0];
        const float4 w1 = wp[1];
#pragma unroll
        for (int bb = 0; bb < 8; ++bb) {
            const float xv  = x[(size_t)(b0 + bb) * I + i];
            // tanh(t) = 1 - 2*rcp(1 + exp2(2*log2e*t)); fused into table index:
            // u = (xn+1)*(T-1)/2 + 0.5 = fma(-(T-1), r, T-0.5)
            const float e2t = ex2(xv * rs2);
            const float r   = rcpa(1.f + e2t);
            const float u   = fmaf(-(float)(T_ENT - 1), r, (float)T_ENT - 0.5f);
            const int idx   = (int)u;             // in [0, T-1], no clamp needed
            union { float4 f4; __half2 h2[4]; } tv;
            tv.f4 = tbl[idx];
            const float2 f0 = __half22float2(tv.h2[0]);
            const float2 f1 = __half22float2(tv.h2[1]);
            const float2 f2 = __half22float2(tv.h2[2]);
            const float2 f3 = __half22float2(tv.h2[3]);
            float s;
            s  = f0.x * w0.x; s = fmaf(f0.y, w0.y, s);
            s  = fmaf(f1.x, w0.z, s); s = fmaf(f1.y, w0.w, s);
            s  = fmaf(f2.x, w1.x, s); s = fmaf(f2.y, w1.y, s);
            s  = fmaf(f3.x, w1.z, s); s = fmaf(f3.y, w1.w, s);
            acc[bb] += s;
        }
    }
    // wave64 butterfly reduce for all 8 accumulators
#pragma unroll
    for (int off = 32; off; off >>= 1) {
#pragma unroll
        for (int bb = 0; bb < 8; ++bb) acc[bb] += __shfl_xor(acc[bb], off, 64);
    }
    if (lane == 0) {
        const float bv = bias[o];
#pragma unroll
        for (int bb = 0; bb < 8; ++bb)
            out[(size_t)(b0 + bb) * O + o] = acc[bb] + bv;
    }
}

// Generic fallback (any G/I/B) — correctness safety net only.
__global__ void kan_generic(const float* __restrict__ x, const float* __restrict__ w,
                            const float* __restrict__ sc, const float* __restrict__ bias,
                            const float* __restrict__ gp, float* __restrict__ out,
                            int B, int I, int O, int G)
{
    const int o    = blockIdx.x;
    const int wid  = threadIdx.x >> 6;
    const int lane = threadIdx.x & 63;
    const int b    = blockIdx.y * 4 + wid;
    if (b >= B) return;

    float acc = 0.f;
    for (int i = lane; i < I; i += 64) {
        const float xv = x[(size_t)b * I + i];
        const float sv = sc[(size_t)o * I + i];
        const float t  = xv / sv;
        const float at = fabsf(t);
        const float e  = ex2(-2.f * LOG2E * at);
        const float th = (1.f - e) / (1.f + e);
        const float xn = __builtin_copysignf(th, t);
        float den = 1e-8f, num = 0.f;
        for (int g = 0; g < G; ++g) {
            const float d  = fabsf(xn - gp[g]);
            const float d3 = d * d * d;
            const float bb = ex2(-d3 * LOG2E);
            den += bb;
            num += bb * w[((size_t)o * I + i) * G + g];
        }
        acc += num / den;
    }
#pragma unroll
    for (int off = 32; off; off >>= 1) acc += __shfl_xor(acc, off, 64);
    if (lane == 0) out[(size_t)b * O + o] = acc + bias[o];
}

extern "C" void kernel_launch(void* const* d_in, const int* in_sizes, int n_in,
                              void* d_out, int out_size, void* d_ws, size_t ws_size,
                              hipStream_t stream) {
    const float* x    = (const float*)d_in[0];
    const float* w    = (const float*)d_in[1];
    const float* sc   = (const float*)d_in[2];
    const float* bias = (const float*)d_in[3];
    const float* gp   = (const float*)d_in[4];
    float* out = (float*)d_out;

    const int O = in_sizes[3];
    const int G = in_sizes[4];
    const int I = in_sizes[2] / O;
    const int B = in_sizes[0] / I;

    if (G == 8 && (I & 63) == 0 && (B & 31) == 0) {
        dim3 grid(O, B / 32);
        kan_tbl<<<grid, 256, 0, stream>>>(x, w, sc, bias, gp, out, B, I, O);
    } else {
        dim3 grid(O, (B + 3) / 4);
        kan_generic<<<grid, 256, 0, stream>>>(x, w, sc, bias, gp, out, B, I, O, G);
    }
}

// Round 4
// 26.587 us; speedup vs baseline: 1.5139x; 1.0879x over previous
//
#include <hip/hip_runtime.h>
#include <hip/hip_fp16.h>

#define DEV __device__ __forceinline__
DEV float ex2(float x)  { return __builtin_amdgcn_exp2f(x); }
DEV float rcpa(float x) { return __builtin_amdgcn_rcpf(x); }

constexpr int   T_ENT = 2048;                  // table entries over xn in [-1,1]
constexpr float LOG2E = 1.4426950408889634f;

typedef _Float16 h2_t __attribute__((ext_vector_type(2)));
typedef __fp16   p2_t __attribute__((ext_vector_type(2)));  // cvt_pkrtz return type
union F4H { float4 f4; uint4 u4; h2_t h[4]; __half2 hh[4]; };

DEV h2_t pkrtz(float a, float b) {
    return __builtin_bit_cast(h2_t, __builtin_amdgcn_cvt_pkrtz(a, b));
}

#if defined(__has_builtin)
#if __has_builtin(__builtin_amdgcn_fdot2)
#define HAVE_FDOT2 1
#endif
#endif

DEV float dot2acc(h2_t a, h2_t b, float c) {
#ifdef HAVE_FDOT2
    return __builtin_amdgcn_fdot2(a, b, c, false);
#else
    return fmaf((float)a.x, (float)b.x, fmaf((float)a.y, (float)b.y, c));
#endif
}

// ---- one-time table build: normalized basis nb(xn), fp16x8 per entry ----
__global__ void kan_build(const float* __restrict__ gp, float4* __restrict__ tbl)
{
    const int e = blockIdx.x * blockDim.x + threadIdx.x;
    if (e >= T_ENT) return;
    const float xn = -1.f + 2.f * (float)e / (float)(T_ENT - 1);
    float bb[8]; float den = 1e-8f;
#pragma unroll
    for (int g = 0; g < 8; ++g) {
        const float d = fabsf(xn - gp[g]);
        bb[g] = ex2(-(d * d * d) * LOG2E);     // exp(-d^3)
        den += bb[g];
    }
    const float rd = 1.f / den;
    F4H u;
#pragma unroll
    for (int j = 0; j < 4; ++j)
        u.h[j] = pkrtz(bb[2*j] * rd, bb[2*j+1] * rd);
    tbl[e] = u.f4;
}

// ---- main: block = (o, 32 b's); 4 waves x 8 b; lanes split I ----
__global__ __launch_bounds__(256)
void kan_main(const float* __restrict__ x, const float* __restrict__ w,
              const float* __restrict__ sc, const float* __restrict__ bias,
              const float4* __restrict__ tblg, float* __restrict__ out,
              int B, int I, int O)
{
    __shared__ uint4 tbl[T_ENT];               // 32 KB
    {
        const uint4* tg = (const uint4*)tblg;
        for (int e = threadIdx.x; e < T_ENT; e += 256) tbl[e] = tg[e];
    }
    __syncthreads();

    const int o    = blockIdx.x;
    const int wid  = threadIdx.x >> 6;
    const int lane = threadIdx.x & 63;
    const int b0   = (blockIdx.y * 4 + wid) * 8;
    if (b0 >= B) return;

    float acc[8] = {0.f,0.f,0.f,0.f,0.f,0.f,0.f,0.f};
    const int nk = I >> 6;
    const float K2 = 2.f * LOG2E;
    for (int k = 0; k < nk; ++k) {
        const int i = (k << 6) + lane;
        const float rs2 = K2 * rcpa(sc[(size_t)o * I + i]);
        const float4* wp = (const float4*)(w + ((size_t)o * I + i) * 8);
        const float4 w0 = wp[0];
        const float4 w1 = wp[1];
        h2_t wh[4];
        wh[0] = pkrtz(w0.x, w0.y);
        wh[1] = pkrtz(w0.z, w0.w);
        wh[2] = pkrtz(w1.x, w1.y);
        wh[3] = pkrtz(w1.z, w1.w);
#pragma unroll
        for (int bb = 0; bb < 8; ++bb) {
            const float xv  = x[(size_t)(b0 + bb) * I + i];
            // idx = (T-1)*(xn+1)/2 + 0.5, xn = tanh via exp2+rcp
            const float e2t = ex2(xv * rs2);
            const float r   = rcpa(1.f + e2t);
            const float u   = fmaf(-(float)(T_ENT - 1), r, (float)T_ENT - 0.5f);
            const int idx   = (int)u;
            F4H tv; tv.u4 = tbl[idx];
            float s = dot2acc(tv.h[0], wh[0], 0.f);
            s = dot2acc(tv.h[1], wh[1], s);
            s = dot2acc(tv.h[2], wh[2], s);
            s = dot2acc(tv.h[3], wh[3], s);
            acc[bb] += s;
        }
    }
#pragma unroll
    for (int off = 32; off; off >>= 1) {
#pragma unroll
        for (int bb = 0; bb < 8; ++bb) acc[bb] += __shfl_xor(acc[bb], off, 64);
    }
    if (lane == 0) {
        const float bv = bias[o];
#pragma unroll
        for (int bb = 0; bb < 8; ++bb)
            out[(size_t)(b0 + bb) * O + o] = acc[bb] + bv;
    }
}

// ---- fallback when d_ws too small: in-block table build ----
__global__ __launch_bounds__(256)
void kan_tbl_inblk(const float* __restrict__ x, const float* __restrict__ w,
                   const float* __restrict__ sc, const float* __restrict__ bias,
                   const float* __restrict__ gp, float* __restrict__ out,
                   int B, int I, int O)
{
    __shared__ uint4 tbl[T_ENT];
    float g8[8];
#pragma unroll
    for (int g = 0; g < 8; ++g) g8[g] = gp[g];
    for (int e = threadIdx.x; e < T_ENT; e += blockDim.x) {
        const float xn = -1.f + 2.f * (float)e / (float)(T_ENT - 1);
        float bb[8]; float den = 1e-8f;
#pragma unroll
        for (int g = 0; g < 8; ++g) {
            const float d = fabsf(xn - g8[g]);
            bb[g] = ex2(-(d * d * d) * LOG2E);
            den += bb[g];
        }
        const float rd = 1.f / den;
        F4H u;
#pragma unroll
        for (int j = 0; j < 4; ++j)
            u.h[j] = pkrtz(bb[2*j] * rd, bb[2*j+1] * rd);
        tbl[e] = u.u4;
    }
    __syncthreads();

    const int o    = blockIdx.x;
    const int wid  = threadIdx.x >> 6;
    const int lane = threadIdx.x & 63;
    const int b0   = (blockIdx.y * 4 + wid) * 8;
    if (b0 >= B) return;

    float acc[8] = {0.f,0.f,0.f,0.f,0.f,0.f,0.f,0.f};
    const int nk = I >> 6;
    const float K2 = 2.f * LOG2E;
    for (int k = 0; k < nk; ++k) {
        const int i = (k << 6) + lane;
        const float rs2 = K2 * rcpa(sc[(size_t)o * I + i]);
        const float4* wp = (const float4*)(w + ((size_t)o * I + i) * 8);
        const float4 w0 = wp[0];
        const float4 w1 = wp[1];
        h2_t wh[4];
        wh[0] = pkrtz(w0.x, w0.y);
        wh[1] = pkrtz(w0.z, w0.w);
        wh[2] = pkrtz(w1.x, w1.y);
        wh[3] = pkrtz(w1.z, w1.w);
#pragma unroll
        for (int bb = 0; bb < 8; ++bb) {
            const float xv  = x[(size_t)(b0 + bb) * I + i];
            const float e2t = ex2(xv * rs2);
            const float r   = rcpa(1.f + e2t);
            const float u   = fmaf(-(float)(T_ENT - 1), r, (float)T_ENT - 0.5f);
            const int idx   = (int)u;
            F4H tv; tv.u4 = tbl[idx];
            float s = dot2acc(tv.h[0], wh[0], 0.f);
            s = dot2acc(tv.h[1], wh[1], s);
            s = dot2acc(tv.h[2], wh[2], s);
            s = dot2acc(tv.h[3], wh[3], s);
            acc[bb] += s;
        }
    }
#pragma unroll
    for (int off = 32; off; off >>= 1) {
#pragma unroll
        for (int bb = 0; bb < 8; ++bb) acc[bb] += __shfl_xor(acc[bb], off, 64);
    }
    if (lane == 0) {
        const float bv = bias[o];
#pragma unroll
        for (int bb = 0; bb < 8; ++bb)
            out[(size_t)(b0 + bb) * O + o] = acc[bb] + bv;
    }
}

// ---- generic fallback (any G/I/B) ----
__global__ void kan_generic(const float* __restrict__ x, const float* __restrict__ w,
                            const float* __restrict__ sc, const float* __restrict__ bias,
                            const float* __restrict__ gp, float* __restrict__ out,
                            int B, int I, int O, int G)
{
    const int o    = blockIdx.x;
    const int wid  = threadIdx.x >> 6;
    const int lane = threadIdx.x & 63;
    const int b    = blockIdx.y * 4 + wid;
    if (b >= B) return;

    float acc = 0.f;
    for (int i = lane; i < I; i += 64) {
        const float xv = x[(size_t)b * I + i];
        const float sv = sc[(size_t)o * I + i];
        const float t  = xv / sv;
        const float at = fabsf(t);
        const float e  = ex2(-2.f * LOG2E * at);
        const float th = (1.f - e) / (1.f + e);
        const float xn = __builtin_copysignf(th, t);
        float den = 1e-8f, num = 0.f;
        for (int g = 0; g < G; ++g) {
            const float d  = fabsf(xn - gp[g]);
            const float d3 = d * d * d;
            const float bb = ex2(-d3 * LOG2E);
            den += bb;
            num += bb * w[((size_t)o * I + i) * G + g];
        }
        acc += num / den;
    }
#pragma unroll
    for (int off = 32; off; off >>= 1) acc += __shfl_xor(acc, off, 64);
    if (lane == 0) out[(size_t)b * O + o] = acc + bias[o];
}

extern "C" void kernel_launch(void* const* d_in, const int* in_sizes, int n_in,
                              void* d_out, int out_size, void* d_ws, size_t ws_size,
                              hipStream_t stream) {
    const float* x    = (const float*)d_in[0];
    const float* w    = (const float*)d_in[1];
    const float* sc   = (const float*)d_in[2];
    const float* bias = (const float*)d_in[3];
    const float* gp   = (const float*)d_in[4];
    float* out = (float*)d_out;

    const int O = in_sizes[3];
    const int G = in_sizes[4];
    const int I = in_sizes[2] / O;
    const int B = in_sizes[0] / I;

    if (G == 8 && (I & 63) == 0 && (B & 31) == 0) {
        dim3 grid(O, B / 32);
        if (ws_size >= (size_t)T_ENT * 16) {
            float4* tblg = (float4*)d_ws;
            kan_build<<<T_ENT / 256, 256, 0, stream>>>(gp, tblg);
            kan_main<<<grid, 256, 0, stream>>>(x, w, sc, bias, tblg, out, B, I, O);
        } else {
            kan_tbl_inblk<<<grid, 256, 0, stream>>>(x, w, sc, bias, gp, out, B, I, O);
        }
    } else {
        dim3 grid(O, (B + 3) / 4);
        kan_generic<<<grid, 256, 0, stream>>>(x, w, sc, bias, gp, out, B, I, O, G);
    }
}

// Round 5
// 20.592 us; speedup vs baseline: 1.9547x; 1.2911x over previous
//
#include <hip/hip_runtime.h>
#include <hip/hip_fp16.h>

#define DEV __device__ __forceinline__
DEV float ex2(float x)  { return __builtin_amdgcn_exp2f(x); }
DEV float rcpa(float x) { return __builtin_amdgcn_rcpf(x); }

constexpr int   T_ENT = 2048;                  // table entries over xn in [-1,1]
constexpr float LOG2E = 1.4426950408889634f;

typedef _Float16 h2_t  __attribute__((ext_vector_type(2)));
typedef _Float16 f16x8 __attribute__((ext_vector_type(8)));
typedef float    f32x4 __attribute__((ext_vector_type(4)));
union F4H { float4 f4; uint4 u4; h2_t h[4]; };

DEV h2_t pkrtz(float a, float b) {
    return __builtin_bit_cast(h2_t, __builtin_amdgcn_cvt_pkrtz(a, b));
}

#if defined(__has_builtin)
#if __has_builtin(__builtin_amdgcn_fdot2)
#define HAVE_FDOT2 1
#endif
#endif

DEV float dot2acc(h2_t a, h2_t b, float c) {
#ifdef HAVE_FDOT2
    return __builtin_amdgcn_fdot2(a, b, c, false);
#else
    return fmaf((float)a.x, (float)b.x, fmaf((float)a.y, (float)b.y, c));
#endif
}

DEV void basis8(float xn, const float* gp, float* bb) {
    float den = 1e-8f;
#pragma unroll
    for (int g = 0; g < 8; ++g) {
        const float d = fabsf(xn - gp[g]);
        bb[g] = ex2(-(d * d * d) * LOG2E);     // exp(-d^3)
        den += bb[g];
    }
    const float rd = 1.f / den;
#pragma unroll
    for (int g = 0; g < 8; ++g) bb[g] *= rd;
}

// ================= specialized fast path (B=512, I=256, O=128, G=8) =========
// ws layout (bytes): [0,1KB) verdict[256] uint; [4KB,36KB) table float4[2048];
// [64KB, 64KB+2MB) A fp16[512][2048]; then Wh fp16[128][2048] (512KB).

// K1: sc-verdicts + basis matrix A (assuming sc==1) + w->fp16 + K3 table.
__global__ __launch_bounds__(256)
void kan_prep(const float* __restrict__ x, const float* __restrict__ w,
              const float* __restrict__ sc, const float* __restrict__ gp,
              unsigned* __restrict__ verd, float4* __restrict__ tbl,
              _Float16* __restrict__ Ah, _Float16* __restrict__ Wh)
{
    const int tidx = threadIdx.x;
    const int blk  = blockIdx.x;
    const int t    = blk * 256 + tidx;          // 0..65535

    // ---- K3 lookup table (blocks 0..7) ----
    if (blk < 8) {
        const int e = t;
        const float xn = -1.f + 2.f * (float)e / (float)(T_ENT - 1);
        float bb[8]; basis8(xn, gp, bb);
        F4H u;
#pragma unroll
        for (int j = 0; j < 4; ++j) u.h[j] = pkrtz(bb[2*j], bb[2*j+1]);
        tbl[e] = u.f4;
    }

    // ---- basis matrix A[b, i*8+g] (2 elems per thread) ----
#pragma unroll
    for (int rep = 0; rep < 2; ++rep) {
        const int e  = t + rep * 65536;         // e = b*256 + i
        const float xv  = x[e];
        const float e2t = ex2(xv * (2.f * LOG2E));
        const float xn  = 1.f - 2.f * rcpa(1.f + e2t);   // tanh(xv)
        float bb[8]; basis8(xn, gp, bb);
        F4H u;
#pragma unroll
        for (int j = 0; j < 4; ++j) u.h[j] = pkrtz(bb[2*j], bb[2*j+1]);
        ((uint4*)Ah)[e] = u.u4;                 // byte off e*16 == (b*2048+i*8)*2
    }

    // ---- w -> fp16 (4 floats per thread) ----
    {
        const float4 wv = ((const float4*)w)[t];
        uint2 p;
        p.x = __builtin_bit_cast(unsigned, pkrtz(wv.x, wv.y));
        p.y = __builtin_bit_cast(unsigned, pkrtz(wv.z, wv.w));
        ((uint2*)Wh)[t] = p;
    }

    // ---- sc != 1 verdict ----
    unsigned bad = 0;
    if (t < 32768) bad = (sc[t] != 1.0f) ? 1u : 0u;
    __shared__ unsigned sbad[4];
    const unsigned wany = (unsigned)__any((int)bad);
    if ((tidx & 63) == 0) sbad[tidx >> 6] = wany;
    __syncthreads();
    if (tidx == 0) verd[blk] = sbad[0] | sbad[1] | sbad[2] | sbad[3];
}

// K2: MFMA GEMM out[b,o] = sum_k A[b,k]*Wh[o,k] + bias[o].  Runs iff sc==1.
__global__ __launch_bounds__(64)
void kan_gemm(const _Float16* __restrict__ Ah, const _Float16* __restrict__ Wh,
              const unsigned* __restrict__ verd, const float* __restrict__ bias,
              float* __restrict__ out)
{
    const int l = threadIdx.x;                  // 0..63
    unsigned f = verd[l] | verd[l + 64] | verd[l + 128] | verd[l + 192];
    if (__any((int)f)) return;                  // some sc != 1 -> K3 handles

    const int tile = blockIdx.x;                // 256 tiles: 32 (m) x 8 (n)
    const int tm = tile >> 3, tn = tile & 7;
    const int lr = l & 15, kb = l >> 4;         // row-in-tile, k-block
    const _Float16* Ar = Ah + (size_t)(tm * 16 + lr) * 2048 + kb * 8;
    const _Float16* Br = Wh + (size_t)(tn * 16 + lr) * 2048 + kb * 8;

    f32x4 acc = {0.f, 0.f, 0.f, 0.f};
#pragma unroll 8
    for (int k = 0; k < 2048; k += 32) {
        const f16x8 a = *(const f16x8*)(Ar + k);
        const f16x8 b = *(const f16x8*)(Br + k);
        acc = __builtin_amdgcn_mfma_f32_16x16x32_f16(a, b, acc, 0, 0, 0);
    }
    // C/D layout (m89): col = lane&15 (-> o), row = (lane>>4)*4 + reg (-> b)
    const int o  = tn * 16 + lr;
    const int b0 = tm * 16 + kb * 4;
    const float bv = bias[o];
#pragma unroll
    for (int r = 0; r < 4; ++r)
        out[(size_t)(b0 + r) * 128 + o] = acc[r] + bv;
}

// ================= table-lookup path (general sc), optionally gated =========
template <bool GATED>
__global__ __launch_bounds__(256)
void kan_main_t(const float* __restrict__ x, const float* __restrict__ w,
                const float* __restrict__ sc, const float* __restrict__ bias,
                const float4* __restrict__ tblg, const unsigned* __restrict__ verd,
                float* __restrict__ out, int B, int I, int O)
{
    if (GATED) {
        const int l = threadIdx.x & 63;
        unsigned f = verd[l] | verd[l + 64] | verd[l + 128] | verd[l + 192];
        if (!__any((int)f)) return;             // sc all ones -> GEMM handled
    }
    __shared__ uint4 tbl[T_ENT];                // 32 KB
    {
        const uint4* tg = (const uint4*)tblg;
        for (int e = threadIdx.x; e < T_ENT; e += 256) tbl[e] = tg[e];
    }
    __syncthreads();

    const int o    = blockIdx.x;
    const int wid  = threadIdx.x >> 6;
    const int lane = threadIdx.x & 63;
    const int b0   = (blockIdx.y * 4 + wid) * 8;
    if (b0 >= B) return;

    float acc[8] = {0.f,0.f,0.f,0.f,0.f,0.f,0.f,0.f};
    const int nk = I >> 6;
    const float K2 = 2.f * LOG2E;
    for (int k = 0; k < nk; ++k) {
        const int i = (k << 6) + lane;
        const float rs2 = K2 * rcpa(sc[(size_t)o * I + i]);
        const float4* wp = (const float4*)(w + ((size_t)o * I + i) * 8);
        const float4 w0 = wp[0];
        const float4 w1 = wp[1];
        h2_t wh[4];
        wh[0] = pkrtz(w0.x, w0.y);
        wh[1] = pkrtz(w0.z, w0.w);
        wh[2] = pkrtz(w1.x, w1.y);
        wh[3] = pkrtz(w1.z, w1.w);
#pragma unroll
        for (int bb = 0; bb < 8; ++bb) {
            const float xv  = x[(size_t)(b0 + bb) * I + i];
            const float e2t = ex2(xv * rs2);
            const float r   = rcpa(1.f + e2t);
            const float u   = fmaf(-(float)(T_ENT - 1), r, (float)T_ENT - 0.5f);
            const int idx   = (int)u;
            F4H tv; tv.u4 = tbl[idx];
            float s = dot2acc(tv.h[0], wh[0], 0.f);
            s = dot2acc(tv.h[1], wh[1], s);
            s = dot2acc(tv.h[2], wh[2], s);
            s = dot2acc(tv.h[3], wh[3], s);
            acc[bb] += s;
        }
    }
#pragma unroll
    for (int off = 32; off; off >>= 1) {
#pragma unroll
        for (int bb = 0; bb < 8; ++bb) acc[bb] += __shfl_xor(acc[bb], off, 64);
    }
    if (lane == 0) {
        const float bv = bias[o];
#pragma unroll
        for (int bb = 0; bb < 8; ++bb)
            out[(size_t)(b0 + bb) * O + o] = acc[bb] + bv;
    }
}

// ---- standalone table build (non-ideal-shape path) ----
__global__ void kan_build(const float* __restrict__ gp, float4* __restrict__ tbl)
{
    const int e = blockIdx.x * blockDim.x + threadIdx.x;
    if (e >= T_ENT) return;
    const float xn = -1.f + 2.f * (float)e / (float)(T_ENT - 1);
    float bb[8]; basis8(xn, gp, bb);
    F4H u;
#pragma unroll
    for (int j = 0; j < 4; ++j) u.h[j] = pkrtz(bb[2*j], bb[2*j+1]);
    tbl[e] = u.f4;
}

// ---- generic fallback (any G/I/B) ----
__global__ void kan_generic(const float* __restrict__ x, const float* __restrict__ w,
                            const float* __restrict__ sc, const float* __restrict__ bias,
                            const float* __restrict__ gp, float* __restrict__ out,
                            int B, int I, int O, int G)
{
    const int o    = blockIdx.x;
    const int wid  = threadIdx.x >> 6;
    const int lane = threadIdx.x & 63;
    const int b    = blockIdx.y * 4 + wid;
    if (b >= B) return;

    float acc = 0.f;
    for (int i = lane; i < I; i += 64) {
        const float xv = x[(size_t)b * I + i];
        const float sv = sc[(size_t)o * I + i];
        const float t  = xv / sv;
        const float at = fabsf(t);
        const float e  = ex2(-2.f * LOG2E * at);
        const float th = (1.f - e) / (1.f + e);
        const float xn = __builtin_copysignf(th, t);
        float den = 1e-8f, num = 0.f;
        for (int g = 0; g < G; ++g) {
            const float d  = fabsf(xn - gp[g]);
            const float d3 = d * d * d;
            const float bb = ex2(-d3 * LOG2E);
            den += bb;
            num += bb * w[((size_t)o * I + i) * G + g];
        }
        acc += num / den;
    }
#pragma unroll
    for (int off = 32; off; off >>= 1) acc += __shfl_xor(acc, off, 64);
    if (lane == 0) out[(size_t)b * O + o] = acc + bias[o];
}

extern "C" void kernel_launch(void* const* d_in, const int* in_sizes, int n_in,
                              void* d_out, int out_size, void* d_ws, size_t ws_size,
                              hipStream_t stream) {
    const float* x    = (const float*)d_in[0];
    const float* w    = (const float*)d_in[1];
    const float* sc   = (const float*)d_in[2];
    const float* bias = (const float*)d_in[3];
    const float* gp   = (const float*)d_in[4];
    float* out = (float*)d_out;

    const int O = in_sizes[3];
    const int G = in_sizes[4];
    const int I = in_sizes[2] / O;
    const int B = in_sizes[0] / I;

    unsigned char* ws = (unsigned char*)d_ws;
    unsigned* verd = (unsigned*)ws;                       // 256 uints
    float4*   tbl  = (float4*)(ws + 4096);                // 32 KB
    _Float16* Ah   = (_Float16*)(ws + 65536);             // 2 MB
    _Float16* Wh   = (_Float16*)(ws + 65536 + 2097152);   // 512 KB

    if (B == 512 && I == 256 && O == 128 && G == 8 && ws_size >= (3u << 20)) {
        kan_prep<<<256, 256, 0, stream>>>(x, w, sc, gp, verd, tbl, Ah, Wh);
        kan_gemm<<<256, 64, 0, stream>>>(Ah, Wh, verd, bias, out);
        kan_main_t<true><<<dim3(O, B / 32), 256, 0, stream>>>(
            x, w, sc, bias, tbl, verd, out, B, I, O);
    } else if (G == 8 && (I & 63) == 0 && (B & 31) == 0 &&
               ws_size >= (size_t)T_ENT * 16) {
        kan_build<<<T_ENT / 256, 256, 0, stream>>>(gp, (float4*)d_ws);
        kan_main_t<false><<<dim3(O, B / 32), 256, 0, stream>>>(
            x, w, sc, bias, (const float4*)d_ws, nullptr, out, B, I, O);
    } else {
        dim3 grid(O, (B + 3) / 4);
        kan_generic<<<grid, 256, 0, stream>>>(x, w, sc, bias, gp, out, B, I, O, G);
    }
}

// Round 6
// 17.103 us; speedup vs baseline: 2.3533x; 1.2040x over previous
//
#include <hip/hip_runtime.h>

#define DEV __device__ __forceinline__
DEV float ex2(float x)  { return __builtin_amdgcn_exp2f(x); }
DEV float rcpa(float x) { return __builtin_amdgcn_rcpf(x); }

constexpr float LOG2E      = 1.4426950408889634f;
constexpr float CBRT_LOG2E = 1.1299472940779f;   // cbrt(log2 e); cube == LOG2E

typedef _Float16 h2_t  __attribute__((ext_vector_type(2)));
typedef _Float16 f16x8 __attribute__((ext_vector_type(8)));
typedef float    f32x4 __attribute__((ext_vector_type(4)));
union F8 { f16x8 v; h2_t h[4]; };

DEV h2_t pkrtz(float a, float b) {
    return __builtin_bit_cast(h2_t, __builtin_amdgcn_cvt_pkrtz(a, b));
}

// =================== fused single-launch kernel (I=256, G=8) ================
// Grid: (B/16, O/16); block 256 thr = 4 waves. Tile 16b x 16o, K=2048 split
// 512/wave. Per-block sc==1 check selects exact-factorization MFMA fast path
// (basis evals land directly in a-fragment registers; W streamed from global
// with inline fp32->fp16) or a direct-compute slow path.
__global__ __launch_bounds__(256)
void kan_fused256(const float* __restrict__ x, const float* __restrict__ w,
                  const float* __restrict__ sc, const float* __restrict__ bias,
                  const float* __restrict__ gp, float* __restrict__ out,
                  int B, int O)
{
    constexpr int I = 256;
    const int tid = threadIdx.x;
    const int b0  = blockIdx.x * 16;
    const int o0  = blockIdx.y * 16;

    __shared__ int   sbad;
    __shared__ f32x4 red[4][64];                 // 4 KB cross-wave reduce

    // ---- per-block sc==1 check over this block's 16 o-rows (coalesced) ----
    bool bad = false;
    {
        const float4* sp = (const float4*)(sc + (size_t)o0 * I);
#pragma unroll
        for (int e = 0; e < 4; ++e) {            // 16*256/4 = 1024 float4
            const float4 v = sp[tid + e * 256];
            bad |= (v.x != 1.f) | (v.y != 1.f) | (v.z != 1.f) | (v.w != 1.f);
        }
    }
    if (tid == 0) sbad = 0;
    __syncthreads();
    if (bad) sbad = 1;
    __syncthreads();

    if (!sbad) {
        // ================= fast path: out = A(basis) * W^T ==================
        const int l   = tid & 63;
        const int kw  = tid >> 6;                // wave id = k-chunk (512 k)
        const int row = l & 15;                  // A-row (b) / B-row (o)
        const int kq  = l >> 4;                  // k-quarter within fragment

        float gs[8];
#pragma unroll
        for (int g = 0; g < 8; ++g) gs[g] = gp[g] * CBRT_LOG2E;

        // ---- basis evals -> a-fragments directly (af[e] == step-e frag) ----
        f16x8 af[16];
        const int ib = kw * 64 + kq;             // i = ib + 4*e
#pragma unroll
        for (int e = 0; e < 16; ++e) {
            const int i = ib + 4 * e;
            const float xv = x[(size_t)(b0 + row) * I + i];
            const float r  = rcpa(1.f + ex2(xv * (2.f * LOG2E)));
            const float ts = fmaf(-2.f * CBRT_LOG2E, r, CBRT_LOG2E); // tanh*C
            float bb[8]; float den = 1e-8f;
#pragma unroll
            for (int g = 0; g < 8; ++g) {
                const float df = ts - gs[g];
                const float d3 = df * df * fabsf(df);
                bb[g] = ex2(-d3);                // == exp(-|d|^3)
                den += bb[g];
            }
            const float rd = rcpa(den);
            F8 u;
            u.h[0] = pkrtz(bb[0] * rd, bb[1] * rd);
            u.h[1] = pkrtz(bb[2] * rd, bb[3] * rd);
            u.h[2] = pkrtz(bb[4] * rd, bb[5] * rd);
            u.h[3] = pkrtz(bb[6] * rd, bb[7] * rd);
            af[e] = u.v;
        }

        // ---- MFMA over k-chunk; W streamed + converted inline ----
        // lane reads w[o0+row][kw*512 + s*32 + kq*8 .. +8] (float idx)
        const float4* wp =
            (const float4*)(w + (size_t)(o0 + row) * 2048 + kw * 512 + kq * 8);
        f32x4 acc = {0.f, 0.f, 0.f, 0.f};
#pragma unroll
        for (int s = 0; s < 16; ++s) {
            const float4 u0 = wp[s * 8];
            const float4 u1 = wp[s * 8 + 1];
            F8 bfu;
            bfu.h[0] = pkrtz(u0.x, u0.y);
            bfu.h[1] = pkrtz(u0.z, u0.w);
            bfu.h[2] = pkrtz(u1.x, u1.y);
            bfu.h[3] = pkrtz(u1.z, u1.w);
            acc = __builtin_amdgcn_mfma_f32_16x16x32_f16(af[s], bfu.v, acc, 0, 0, 0);
        }

        // ---- cross-wave k-reduce + epilogue ----
        red[kw][l] = acc;
        __syncthreads();
        const int rr = tid >> 6;                 // C/D reg index
        const int ll = tid & 63;
        const float sum = ((const float*)&red[0][ll])[rr]
                        + ((const float*)&red[1][ll])[rr]
                        + ((const float*)&red[2][ll])[rr]
                        + ((const float*)&red[3][ll])[rr];
        // C/D map (m89): col = lane&15 -> o, row = (lane>>4)*4 + reg -> b
        const int oo = o0 + (ll & 15);
        const int bb2 = b0 + (ll >> 4) * 4 + rr;
        out[(size_t)bb2 * O + oo] = sum + bias[oo];
    } else {
        // ================= slow path: direct compute (general sc) ===========
        const int bt = b0 + (tid >> 4);
        const int ot = o0 + (tid & 15);
        float acc = 0.f;
        for (int i = 0; i < I; ++i) {
            const float xv = x[(size_t)bt * I + i];
            const float sv = sc[(size_t)ot * I + i];
            const float t  = xv / sv;
            const float e  = ex2(-2.f * LOG2E * fabsf(t));
            const float th = (1.f - e) / (1.f + e);
            const float xn = __builtin_copysignf(th, t);
            const float4* wv = (const float4*)(w + ((size_t)ot * I + i) * 8);
            const float4 w0 = wv[0];
            const float4 w1 = wv[1];
            const float wb[8] = {w0.x, w0.y, w0.z, w0.w, w1.x, w1.y, w1.z, w1.w};
            float den = 1e-8f, num = 0.f;
#pragma unroll
            for (int g = 0; g < 8; ++g) {
                const float d  = fabsf(xn - gp[g]);
                const float d3 = d * d * d;
                const float bv = ex2(-d3 * LOG2E);
                den += bv;
                num += bv * wb[g];
            }
            acc += num / den;
        }
        out[(size_t)bt * O + ot] = acc + bias[ot];
    }
}

// =================== generic fallback (any G/I/B/O) =========================
__global__ void kan_generic(const float* __restrict__ x, const float* __restrict__ w,
                            const float* __restrict__ sc, const float* __restrict__ bias,
                            const float* __restrict__ gp, float* __restrict__ out,
                            int B, int I, int O, int G)
{
    const int o    = blockIdx.x;
    const int wid  = threadIdx.x >> 6;
    const int lane = threadIdx.x & 63;
    const int b    = blockIdx.y * 4 + wid;
    if (b >= B) return;

    float acc = 0.f;
    for (int i = lane; i < I; i += 64) {
        const float xv = x[(size_t)b * I + i];
        const float sv = sc[(size_t)o * I + i];
        const float t  = xv / sv;
        const float at = fabsf(t);
        const float e  = ex2(-2.f * LOG2E * at);
        const float th = (1.f - e) / (1.f + e);
        const float xn = __builtin_copysignf(th, t);
        float den = 1e-8f, num = 0.f;
        for (int g = 0; g < G; ++g) {
            const float d  = fabsf(xn - gp[g]);
            const float d3 = d * d * d;
            const float bb = ex2(-d3 * LOG2E);
            den += bb;
            num += bb * w[((size_t)o * I + i) * G + g];
        }
        acc += num / den;
    }
#pragma unroll
    for (int off = 32; off; off >>= 1) acc += __shfl_xor(acc, off, 64);
    if (lane == 0) out[(size_t)b * O + o] = acc + bias[o];
}

extern "C" void kernel_launch(void* const* d_in, const int* in_sizes, int n_in,
                              void* d_out, int out_size, void* d_ws, size_t ws_size,
                              hipStream_t stream) {
    const float* x    = (const float*)d_in[0];
    const float* w    = (const float*)d_in[1];
    const float* sc   = (const float*)d_in[2];
    const float* bias = (const float*)d_in[3];
    const float* gp   = (const float*)d_in[4];
    float* out = (float*)d_out;

    const int O = in_sizes[3];
    const int G = in_sizes[4];
    const int I = in_sizes[2] / O;
    const int B = in_sizes[0] / I;

    if (I == 256 && G == 8 && (B & 15) == 0 && (O & 15) == 0) {
        dim3 grid(B / 16, O / 16);
        kan_fused256<<<grid, 256, 0, stream>>>(x, w, sc, bias, gp, out, B, O);
    } else {
        dim3 grid(O, (B + 3) / 4);
        kan_generic<<<grid, 256, 0, stream>>>(x, w, sc, bias, gp, out, B, I, O, G);
    }
}

// Round 7
// 12.488 us; speedup vs baseline: 3.2231x; 1.3696x over previous
//
#include <hip/hip_runtime.h>

#define DEV __device__ __forceinline__
DEV float ex2(float x)  { return __builtin_amdgcn_exp2f(x); }
DEV float rcpa(float x) { return __builtin_amdgcn_rcpf(x); }

constexpr float LOG2E      = 1.4426950408889634f;
constexpr float CBRT_LOG2E = 1.1299472940779f;   // cbrt(log2 e); cube == LOG2E

typedef _Float16 h2_t  __attribute__((ext_vector_type(2)));
typedef _Float16 f16x8 __attribute__((ext_vector_type(8)));
typedef float    f32x4 __attribute__((ext_vector_type(4)));
union F8 { f16x8 v; h2_t h[4]; };

DEV h2_t pkrtz(float a, float b) {
    return __builtin_bit_cast(h2_t, __builtin_amdgcn_cvt_pkrtz(a, b));
}

// =================== fused single-launch kernel (I=256, G=8) ================
// Grid: (B/16, O/16) = 256 blocks; block = 1024 thr = 16 waves (4/SIMD for
// latency hiding). Tile 16b x 16o; K = 2048 split 128/wave (4 MFMA steps).
// sc==1 check is speculative: its load flies while basis evals compute.
__global__ __launch_bounds__(1024)
void kan_fused1k(const float* __restrict__ x, const float* __restrict__ w,
                 const float* __restrict__ sc, const float* __restrict__ bias,
                 const float* __restrict__ gp, float* __restrict__ out,
                 int B, int O)
{
    constexpr int I = 256;
    const int tid = threadIdx.x;
    const int b0  = blockIdx.x * 16;
    const int o0  = blockIdx.y * 16;

    __shared__ int   sbad;
    __shared__ f32x4 red[16][64];                // 16 KB cross-wave reduce

    if (tid == 0) sbad = 0;

    // ---- speculative sc==1 check: 16 rows x 256 = 1024 float4, 1/thread ----
    bool bad;
    {
        const float4 v = ((const float4*)(sc + (size_t)o0 * I))[tid];
        bad = (v.x != 1.f) | (v.y != 1.f) | (v.z != 1.f) | (v.w != 1.f);
    }

    const int l   = tid & 63;
    const int kw  = tid >> 6;                    // wave id: k-chunk of 16 i
    const int row = l & 15;                      // A-row (b) / B-row (o)
    const int kq  = l >> 4;                      // k-quarter within fragment

    float gs[8];
#pragma unroll
    for (int g = 0; g < 8; ++g) gs[g] = gp[g] * CBRT_LOG2E;

    // ---- speculative basis evals -> a-fragments (i = kw*16 + e*4 + kq) ----
    f16x8 af[4];
#pragma unroll
    for (int e = 0; e < 4; ++e) {
        const int i = kw * 16 + e * 4 + kq;
        const float xv = x[(size_t)(b0 + row) * I + i];
        const float r  = rcpa(1.f + ex2(xv * (2.f * LOG2E)));
        const float ts = fmaf(-2.f * CBRT_LOG2E, r, CBRT_LOG2E); // tanh * C
        float bb[8]; float den = 1e-8f;
#pragma unroll
        for (int g = 0; g < 8; ++g) {
            const float df = ts - gs[g];
            const float d3 = df * df * fabsf(df);
            bb[g] = ex2(-d3);                    // == exp(-|d|^3)
            den += bb[g];
        }
        const float rd = rcpa(den);
        F8 u;
        u.h[0] = pkrtz(bb[0] * rd, bb[1] * rd);
        u.h[1] = pkrtz(bb[2] * rd, bb[3] * rd);
        u.h[2] = pkrtz(bb[4] * rd, bb[5] * rd);
        u.h[3] = pkrtz(bb[6] * rd, bb[7] * rd);
        af[e] = u.v;
    }

    __syncthreads();                             // sbad=0 visible; evals done
    if (bad) sbad = 1;
    __syncthreads();

    if (!sbad) {
        // ---- MFMA over this wave's 128-k chunk; W streamed + converted ----
        const float4* wp =
            (const float4*)(w + (size_t)(o0 + row) * 2048 + kw * 128 + kq * 8);
        f32x4 acc = {0.f, 0.f, 0.f, 0.f};
#pragma unroll
        for (int e = 0; e < 4; ++e) {
            const float4 u0 = wp[e * 8];
            const float4 u1 = wp[e * 8 + 1];
            F8 bf;
            bf.h[0] = pkrtz(u0.x, u0.y);
            bf.h[1] = pkrtz(u0.z, u0.w);
            bf.h[2] = pkrtz(u1.x, u1.y);
            bf.h[3] = pkrtz(u1.z, u1.w);
            acc = __builtin_amdgcn_mfma_f32_16x16x32_f16(af[e], bf.v, acc, 0, 0, 0);
        }

        // ---- 16-way cross-wave k-reduce + epilogue ----
        red[kw][l] = acc;
        __syncthreads();
        if (tid < 256) {
            const int ll = tid & 63;
            const int rr = tid >> 6;             // C/D reg index
            float s = 0.f;
#pragma unroll
            for (int wv = 0; wv < 16; ++wv)
                s += ((const float*)&red[wv][ll])[rr];
            // C/D map (m89): col = lane&15 -> o, row = (lane>>4)*4 + reg -> b
            const int oo  = o0 + (ll & 15);
            const int bb2 = b0 + (ll >> 4) * 4 + rr;
            out[(size_t)bb2 * O + oo] = s + bias[oo];
        }
    } else {
        // ---- slow path: direct compute (general sc), 1 thread/output ----
        if (tid < 256) {
            const int bt = b0 + (tid >> 4);
            const int ot = o0 + (tid & 15);
            float acc = 0.f;
            for (int i = 0; i < I; ++i) {
                const float xv = x[(size_t)bt * I + i];
                const float sv = sc[(size_t)ot * I + i];
                const float t  = xv / sv;
                const float e  = ex2(-2.f * LOG2E * fabsf(t));
                const float th = (1.f - e) / (1.f + e);
                const float xn = __builtin_copysignf(th, t);
                const float4* wv = (const float4*)(w + ((size_t)ot * I + i) * 8);
                const float4 w0 = wv[0];
                const float4 w1 = wv[1];
                const float wb[8] = {w0.x, w0.y, w0.z, w0.w,
                                     w1.x, w1.y, w1.z, w1.w};
                float den = 1e-8f, num = 0.f;
#pragma unroll
                for (int g = 0; g < 8; ++g) {
                    const float d  = fabsf(xn - gp[g]);
                    const float d3 = d * d * d;
                    const float bv = ex2(-d3 * LOG2E);
                    den += bv;
                    num += bv * wb[g];
                }
                acc += num / den;
            }
            out[(size_t)bt * O + ot] = acc + bias[ot];
        }
    }
}

// =================== generic fallback (any G/I/B/O) =========================
__global__ void kan_generic(const float* __restrict__ x, const float* __restrict__ w,
                            const float* __restrict__ sc, const float* __restrict__ bias,
                            const float* __restrict__ gp, float* __restrict__ out,
                            int B, int I, int O, int G)
{
    const int o    = blockIdx.x;
    const int wid  = threadIdx.x >> 6;
    const int lane = threadIdx.x & 63;
    const int b    = blockIdx.y * 4 + wid;
    if (b >= B) return;

    float acc = 0.f;
    for (int i = lane; i < I; i += 64) {
        const float xv = x[(size_t)b * I + i];
        const float sv = sc[(size_t)o * I + i];
        const float t  = xv / sv;
        const float at = fabsf(t);
        const float e  = ex2(-2.f * LOG2E * at);
        const float th = (1.f - e) / (1.f + e);
        const float xn = __builtin_copysignf(th, t);
        float den = 1e-8f, num = 0.f;
        for (int g = 0; g < G; ++g) {
            const float d  = fabsf(xn - gp[g]);
            const float d3 = d * d * d;
            const float bb = ex2(-d3 * LOG2E);
            den += bb;
            num += bb * w[((size_t)o * I + i) * G + g];
        }
        acc += num / den;
    }
#pragma unroll
    for (int off = 32; off; off >>= 1) acc += __shfl_xor(acc, off, 64);
    if (lane == 0) out[(size_t)b * O + o] = acc + bias[o];
}

extern "C" void kernel_launch(void* const* d_in, const int* in_sizes, int n_in,
                              void* d_out, int out_size, void* d_ws, size_t ws_size,
                              hipStream_t stream) {
    const float* x    = (const float*)d_in[0];
    const float* w    = (const float*)d_in[1];
    const float* sc   = (const float*)d_in[2];
    const float* bias = (const float*)d_in[3];
    const float* gp   = (const float*)d_in[4];
    float* out = (float*)d_out;

    const int O = in_sizes[3];
    const int G = in_sizes[4];
    const int I = in_sizes[2] / O;
    const int B = in_sizes[0] / I;

    if (I == 256 && G == 8 && (B & 15) == 0 && (O & 15) == 0) {
        dim3 grid(B / 16, O / 16);
        kan_fused1k<<<grid, 1024, 0, stream>>>(x, w, sc, bias, gp, out, B, O);
    } else {
        dim3 grid(O, (B + 3) / 4);
        kan_generic<<<grid, 256, 0, stream>>>(x, w, sc, bias, gp, out, B, I, O, G);
    }
}